// Round 1
// baseline (697.385 us; speedup 1.0000x reference)
//
#include <hip/hip_runtime.h>
#include <math.h>

#define S 384
#define NE 191
#define N0 192
#define MAXADJ 32

// ---------------------------------------------------------------------------
// setup: precompute W = exp(-psiE), WT, phie; zero state; build CSR adjacency
// ---------------------------------------------------------------------------
__global__ __launch_bounds__(256) void k_setup(
    const int* __restrict__ E1f, const int* __restrict__ E1b,
    const float* __restrict__ cost, const float* __restrict__ constr,
    float* __restrict__ W, float* __restrict__ WT, float* __restrict__ PHIE,
    float* __restrict__ SF0, float* __restrict__ SB0,
    float* __restrict__ MSGF, float* __restrict__ MSGB,
    float* __restrict__ MB, float* __restrict__ MAXB,
    float* __restrict__ U, float* __restrict__ V,
    int* __restrict__ cntF, int* __restrict__ adjF,
    int* __restrict__ cntB, int* __restrict__ adjB)
{
    int tid  = blockIdx.x * blockDim.x + threadIdx.x;
    int nthr = gridDim.x * blockDim.x;

    for (int idx = tid; idx < S * S; idx += nthr) {
        int i = idx / S, j = idx % S;
        // cf: top-left constr, top-right 0, bottom rows 1
        float cf = (i < N0) ? ((j < N0) ? constr[i * N0 + j] : 0.f) : 1.f;
        float w  = expf(-50.f * (1.f - cf));   // exp(-psiE[i][j]), psiE = LAM*(1-cf)/EPS
        W[idx]       = w;                       // W[i][j]
        WT[j * S + i] = w;                      // WT[j][i]
        // phie[i][j] = phi[i][j]/EPS = cost_p[j][i]*10
        float ph = (i < N0 && j < N0) ? 10.f * cost[j * N0 + i] : 0.f;
        PHIE[idx] = ph;
        SF0[idx]  = 0.f;
        SB0[idx]  = 0.f;
    }
    for (int idx = tid; idx < S * NE; idx += nthr) {
        MSGF[idx] = 0.f; MSGB[idx] = 0.f; MB[idx] = 1.f;  // Mb=exp(0-0)=1 at init
    }
    for (int idx = tid; idx < NE; idx += nthr) MAXB[idx] = 0.f;
    for (int idx = tid; idx < S; idx += nthr) { U[idx] = 0.f; V[idx] = 0.f; }

    // adjacency: for each column s, list of edges with dst == s (deterministic order)
    for (int s = tid; s < S; s += nthr) {
        int cf_ = 0, cb_ = 0;
        for (int e = 0; e < NE; ++e) {
            if (E1f[2 * e + 1] == s && cf_ < MAXADJ) adjF[s * MAXADJ + cf_++] = e;
            if (E1b[2 * e + 1] == s && cb_ < MAXADJ) adjB[s * MAXADJ + cb_++] = e;
        }
        cntF[s] = cf_;
        cntB[s] = cb_;
    }
}

// ---------------------------------------------------------------------------
// u[j] = LSE_i( SF[i,j] + SB[i,j] - PHIE[i,j] - V[i] ), one block per column j
// ---------------------------------------------------------------------------
__global__ __launch_bounds__(256) void k_ucol(
    const float* __restrict__ SF, const float* __restrict__ SB,
    const float* __restrict__ PHIE, const float* __restrict__ V,
    float* __restrict__ U)
{
    int j = blockIdx.x;
    int t = threadIdx.x;
    __shared__ float red[256];

    int i1 = t, i2 = t + 256;
    float x1 = SF[i1 * S + j] + SB[i1 * S + j] - PHIE[i1 * S + j] - V[i1];
    float x2 = -1e30f;
    if (i2 < S) x2 = SF[i2 * S + j] + SB[i2 * S + j] - PHIE[i2 * S + j] - V[i2];

    red[t] = fmaxf(x1, x2);
    __syncthreads();
    for (int o = 128; o > 0; o >>= 1) {
        if (t < o) red[t] = fmaxf(red[t], red[t + o]);
        __syncthreads();
    }
    float M = red[0];
    __syncthreads();

    float sum = expf(x1 - M) + ((i2 < S) ? expf(x2 - M) : 0.f);
    red[t] = sum;
    __syncthreads();
    for (int o = 128; o > 0; o >>= 1) {
        if (t < o) red[t] += red[t + o];
        __syncthreads();
    }
    if (t == 0) U[j] = M + logf(red[0]);
}

// ---------------------------------------------------------------------------
// v[i] = LSE_j( SF[i,j] + SB[i,j] - PHIE[i,j] - U[j] ), one block per row i
// ---------------------------------------------------------------------------
__global__ __launch_bounds__(256) void k_vrow(
    const float* __restrict__ SF, const float* __restrict__ SB,
    const float* __restrict__ PHIE, const float* __restrict__ U,
    float* __restrict__ V)
{
    int i = blockIdx.x;
    int t = threadIdx.x;
    __shared__ float red[256];

    int j1 = t, j2 = t + 256;
    float x1 = SF[i * S + j1] + SB[i * S + j1] - PHIE[i * S + j1] - U[j1];
    float x2 = -1e30f;
    if (j2 < S) x2 = SF[i * S + j2] + SB[i * S + j2] - PHIE[i * S + j2] - U[j2];

    red[t] = fmaxf(x1, x2);
    __syncthreads();
    for (int o = 128; o > 0; o >>= 1) {
        if (t < o) red[t] = fmaxf(red[t], red[t + o]);
        __syncthreads();
    }
    float M = red[0];
    __syncthreads();

    float sum = expf(x1 - M) + ((j2 < S) ? expf(x2 - M) : 0.f);
    red[t] = sum;
    __syncthreads();
    for (int o = 128; o > 0; o >>= 1) {
        if (t < o) red[t] += red[t + o];
        __syncthreads();
    }
    if (t == 0) V[i] = M + logf(red[0]);
}

// ---------------------------------------------------------------------------
// msg update: y[s,e] = sum_k Arows[k][s] * B[k][e]   (tiled fp32 GEMM)
// msg[s,e] = 0.5*(msg + (phie[s,d]+u[d]+v[s]-SFu[s,d]-SBu[s,d]) + maxX[e] + log y)
//   P3 (msg_f): Arows=W,  B=Mb, d=dst_f, SFu=sf_cur,  SBu=sb_cur
//   P5 (msg_b): Arows=WT, B=Mf, d=dst_b, SFu=sf_next, SBu=sb_cur
// ---------------------------------------------------------------------------
#define TR 32
#define TC 32
#define TK 32
__global__ __launch_bounds__(256) void k_gemm_msg(
    const float* __restrict__ Arows,   // [S][S]
    const float* __restrict__ Bmat,    // [S][NE]
    const float* __restrict__ maxX,    // [NE]
    float* __restrict__ msg,           // [S][NE] in/out
    const int* __restrict__ edges,     // E1x, dst = edges[2e+1]
    const float* __restrict__ PHIE,
    const float* __restrict__ U, const float* __restrict__ V,
    const float* __restrict__ SFu, const float* __restrict__ SBu)
{
    __shared__ float la[TK][TR + 2];
    __shared__ float lb[TK][TC + 2];

    int r0 = (blockIdx.x % (S / TR)) * TR;       // 12 row tiles
    int e0 = (blockIdx.x / (S / TR)) * TC;       // 6 col tiles
    int t  = threadIdx.x;
    int tx = t & 15, ty = t >> 4;

    float acc[2][2] = {{0.f, 0.f}, {0.f, 0.f}};

    for (int k0 = 0; k0 < S; k0 += TK) {
        for (int q = t; q < TK * TR; q += 256) {
            int k = q >> 5, r = q & 31;
            la[k][r] = Arows[(k0 + k) * S + r0 + r];
        }
        for (int q = t; q < TK * TC; q += 256) {
            int k = q >> 5, c = q & 31;
            int e = e0 + c;
            lb[k][c] = (e < NE) ? Bmat[(k0 + k) * NE + e] : 0.f;
        }
        __syncthreads();
#pragma unroll 8
        for (int k = 0; k < TK; ++k) {
            float a0 = la[k][2 * ty], a1 = la[k][2 * ty + 1];
            float b0 = lb[k][2 * tx], b1 = lb[k][2 * tx + 1];
            acc[0][0] += a0 * b0; acc[0][1] += a0 * b1;
            acc[1][0] += a1 * b0; acc[1][1] += a1 * b1;
        }
        __syncthreads();
    }

    for (int dr = 0; dr < 2; ++dr) {
        int s = r0 + 2 * ty + dr;
        for (int dc = 0; dc < 2; ++dc) {
            int e = e0 + 2 * tx + dc;
            if (e < NE) {
                int d = edges[2 * e + 1];
                float term = PHIE[s * S + d] + U[d] + V[s]
                           - SFu[s * S + d] - SBu[s * S + d];
                float old = msg[s * NE + e];
                msg[s * NE + e] = 0.5f * (old + term + maxX[e] + logf(acc[dr][dc]));
            }
        }
    }
}

// ---------------------------------------------------------------------------
// post: (1) sum_next[:,s] = sum over edges e with dst==s of msg[:,e]  (CSR gather)
//       (2) for e<NE: maxX[e] = max_i(-msg[i,e]); Mx[i,e] = exp(-msg - maxX)
// ---------------------------------------------------------------------------
__global__ __launch_bounds__(256) void k_post(
    const float* __restrict__ msg,
    const int* __restrict__ cnt, const int* __restrict__ adj,
    float* __restrict__ sum_next,
    float* __restrict__ Mx, float* __restrict__ maxX)
{
    int b = blockIdx.x;
    int t = threadIdx.x;

    int c = cnt[b];
    for (int r = t; r < S; r += 256) {
        float a = 0.f;
        for (int q = 0; q < c; ++q) a += msg[r * NE + adj[b * MAXADJ + q]];
        sum_next[r * S + b] = a;
    }

    if (b < NE) {
        __shared__ float red[256];
        float mn = 1e30f;
        for (int r = t; r < S; r += 256) mn = fminf(mn, msg[r * NE + b]);
        red[t] = mn;
        __syncthreads();
        for (int o = 128; o > 0; o >>= 1) {
            if (t < o) red[t] = fminf(red[t], red[t + o]);
            __syncthreads();
        }
        mn = red[0];
        if (t == 0) maxX[b] = -mn;
        for (int r = t; r < S; r += 256)
            Mx[r * NE + b] = expf(mn - msg[r * NE + b]);
    }
}

// ---------------------------------------------------------------------------
// out[a,b] = exp(min(SF[b,a]+SB[b,a]-PHIE[b,a]-U[a]-V[b], 0))   (transposed)
// ---------------------------------------------------------------------------
__global__ __launch_bounds__(256) void k_final(
    const float* __restrict__ SF, const float* __restrict__ SB,
    const float* __restrict__ PHIE, const float* __restrict__ U,
    const float* __restrict__ V, float* __restrict__ out)
{
    int idx = blockIdx.x * blockDim.x + threadIdx.x;
    if (idx >= S * S) return;
    int a = idx / S, b = idx % S;
    int ij = b * S + a;
    float lp = fminf(SF[ij] + SB[ij] - PHIE[ij] - U[a] - V[b], 0.f);
    out[idx] = expf(lp);
}

// ---------------------------------------------------------------------------
extern "C" void kernel_launch(void* const* d_in, const int* in_sizes, int n_in,
                              void* d_out, int out_size, void* d_ws, size_t ws_size,
                              hipStream_t stream)
{
    const int*   E1f    = (const int*)d_in[0];
    const int*   E1b    = (const int*)d_in[1];
    // d_in[2] (E2f) unused by forward
    const float* cost   = (const float*)d_in[3];
    const float* constr = (const float*)d_in[4];

    const int SS = S * S;   // 147456
    const int SE = S * NE;  // 73344

    float* ws   = (float*)d_ws;
    float* W    = ws;
    float* WT   = W + SS;
    float* PHIE = WT + SS;
    float* SFb[2] = { PHIE + SS, PHIE + 2 * SS };
    float* SBb[2] = { PHIE + 3 * SS, PHIE + 4 * SS };
    float* MSGF = PHIE + 5 * SS;
    float* MSGB = MSGF + SE;
    float* MF   = MSGB + SE;
    float* MB   = MF + SE;
    float* U    = MB + SE;
    float* V    = U + S;
    float* MAXF = V + S;
    float* MAXB = MAXF + 256;
    int*   ints = (int*)(MAXB + 256);
    int*   cntF = ints;
    int*   cntB = cntF + S;
    int*   adjF = cntB + S;
    int*   adjB = adjF + S * MAXADJ;

    k_setup<<<384, 256, 0, stream>>>(E1f, E1b, cost, constr,
                                     W, WT, PHIE, SFb[0], SBb[0],
                                     MSGF, MSGB, MB, MAXB, U, V,
                                     cntF, adjF, cntB, adjB);

    const int gemm_grid = (S / TR) * ((NE + TC - 1) / TC);  // 12*6 = 72

    for (int step = 0; step < 8; ++step) {
        float* sfc = SFb[step & 1];
        float* sfn = SFb[1 - (step & 1)];
        float* sbc = SBb[step & 1];
        float* sbn = SBb[1 - (step & 1)];

        k_ucol<<<S, 256, 0, stream>>>(sfc, sbc, PHIE, V, U);
        k_vrow<<<S, 256, 0, stream>>>(sfc, sbc, PHIE, U, V);
        // msg_f: y = WT @ Mb  ->  Arows = W
        k_gemm_msg<<<gemm_grid, 256, 0, stream>>>(W, MB, MAXB, MSGF, E1f,
                                                  PHIE, U, V, sfc, sbc);
        k_post<<<S, 256, 0, stream>>>(MSGF, cntF, adjF, sfn, MF, MAXF);
        // msg_b: y = W @ Mf  ->  Arows = WT ; uses NEW sum_f (sfn), old sum_b
        k_gemm_msg<<<gemm_grid, 256, 0, stream>>>(WT, MF, MAXF, MSGB, E1b,
                                                  PHIE, U, V, sfn, sbc);
        k_post<<<S, 256, 0, stream>>>(MSGB, cntB, adjB, sbn, MB, MAXB);
    }

    k_final<<<(SS + 255) / 256, 256, 0, stream>>>(SFb[0], SBb[0], PHIE, U, V,
                                                  (float*)d_out);
}